// Round 16
// baseline (124.569 us; speedup 1.0000x reference)
//
#include <hip/hip_runtime.h>
#include <hip/hip_bf16.h>
#include <math.h>

#define BZ 16
#define SEQ 64
#define CID 207
#define DIN 64
#define OCN 128
#define NN (BZ*CID)        // 3312
#define NE (NN*16)         // 52992
#define ICD (CID*DIN)      // 13248
#define KW 3
#define NKPAD 416          // kstep padded to 32*13
#define NKC 32             // K-split chunks
#define KSPC 13            // ksteps per chunk
#define XTOT ((size_t)BZ*SEQ*ICD)   // 13565952
#define TCH 8              // t-chunk for gather
#define NCHUNK (SEQ/TCH)   // 8
#define CAP 64             // padded CSR capacity per node (max observed deg ~45)
#define WFSTEP (3*8*64*8)  // wf elems per kstep = 12288

// k1 block ranges: cvtmean [0,832) | scatter [832,1039) | wprep [1039,2703)
#define CVB 832
#define SCB 207
#define WPB (NKPAD*4)

typedef __attribute__((ext_vector_type(8))) short bf16x8;
typedef __attribute__((ext_vector_type(4))) float f32x4;
typedef unsigned short u16;
typedef unsigned int u32;

__device__ __forceinline__ float bflo(u32 u) {
    u32 v = u << 16;
    return __builtin_bit_cast(float, v);
}
__device__ __forceinline__ float bfhi(u32 u) {
    u32 v = u & 0xFFFF0000u;
    return __builtin_bit_cast(float, v);
}
__device__ __forceinline__ u16 f2bf(float f) {
    __hip_bfloat16 h = __float2bfloat16(f);
    return __builtin_bit_cast(u16, h);
}
__device__ __forceinline__ u32 packbf(float f0, float f1) {
    return ((u32)f2bf(f1) << 16) | (u32)f2bf(f0);
}
__device__ __forceinline__ void fma8(float* acc, float a, uint4 v) {
    acc[0] += a * bflo(v.x); acc[1] += a * bfhi(v.x);
    acc[2] += a * bflo(v.y); acc[3] += a * bfhi(v.y);
    acc[4] += a * bflo(v.z); acc[5] += a * bfhi(v.z);
    acc[6] += a * bflo(v.w); acc[7] += a * bfhi(v.w);
}

// ---------------- tiny zero kernel ----------------
__global__ __launch_bounds__(256) void zero_kernel(int* __restrict__ p, int n) {
    int i = threadIdx.x;
    for (; i < n; i += 256) p[i] = 0;
}

// ---------------- k1: cvtmean(t-split x4) | scatter(padded CSR) | wprep(32-oc) ----------------
__global__ __launch_bounds__(256) void k1_kernel(const float* __restrict__ x,
                                                 u16* __restrict__ xt,
                                                 float* __restrict__ meanp,
                                                 const int* __restrict__ esrc,
                                                 const int* __restrict__ edst,
                                                 int* __restrict__ fill,
                                                 int* __restrict__ csr,
                                                 const float* __restrict__ cw,
                                                 u16* __restrict__ wf) {
    __shared__ float s_cw[32][100];   // wprep scratch, 12.8 KB
    int bid = blockIdx.x;
    int tid = threadIdx.x;
    if (bid < CVB) {
        // ---- cvtmean: 16 t's per block; partial sum -> meanp[tq] ----
        int bb = bid / 52;
        int rem = bid - bb * 52;
        int cg = rem >> 2;            // 0..12
        int tq = rem & 3;             // t-quarter
        int cl = tid >> 4;
        int dq = (tid & 15) << 2;
        int c = cg * 16 + cl;
        if (c >= CID) return;
        int n = bb * CID + c;
        const float* px = x + (size_t)bb * SEQ * ICD + (size_t)(tq * 16) * ICD + (size_t)c * DIN + dq;
        u16* pxt = xt + ((size_t)(tq * 16) * NN + n) * DIN + dq;
        float ax = 0.f, ay = 0.f, az = 0.f, aw = 0.f;
        #pragma unroll 4
        for (int t = 0; t < 16; ++t) {
            float4 v = *(const float4*)(px + (size_t)t * ICD);
            ax += v.x; ay += v.y; az += v.z; aw += v.w;
            uint2 w2;
            w2.x = packbf(v.x, v.y);
            w2.y = packbf(v.z, v.w);
            *(uint2*)(pxt + (size_t)t * NN * DIN) = w2;
        }
        *(float4*)(meanp + ((size_t)tq * NN + n) * DIN + dq) = make_float4(ax, ay, az, aw);
    } else if (bid < CVB + SCB) {
        // ---- scatter into padded CSR (fill zeroed by zero_kernel; fill[n] becomes deg[n]) ----
        int e = (bid - CVB) * 256 + tid;   // exactly NE
        int d0 = edst[e];
        int pos = atomicAdd(&fill[d0], 1);
        if (pos < CAP) csr[(d0 << 6) + pos] = esrc[e];
    } else {
        // ---- wprep: conv weight -> MFMA B-fragment layout, 32 oc (2 nt) per block ----
        int wkb = bid - (CVB + SCB);
        int kstep = wkb >> 2;             // 0..415
        int p = wkb & 3;                  // oc quarter
        int ic0 = kstep * 32;
        int col0 = ic0 * 3;
        {
            int oc_l = tid >> 3;
            int seg = tid & 7;
            const float* src = cw + (size_t)(p * 32 + oc_l) * (ICD * KW) + col0 + seg * 12;
            #pragma unroll
            for (int uu = 0; uu < 12; ++uu) {
                int col = seg * 12 + uu;
                float v = (col0 + col < ICD * 3) ? src[uu] : 0.f;
                s_cw[oc_l][col] = v;
            }
        }
        __syncthreads();
        #pragma unroll
        for (int r = 0; r < 2; ++r) {
            int f = tid + 256 * r;        // 0..511, use 0..383
            if (f < 384) {
                int lane = f & 63;
                int g = f >> 6;           // 0..5
                int ntl = g & 1;
                int w = g >> 1;
                int nt = p * 2 + ntl;
                int row = ntl * 16 + (lane & 15);
                int cb = 8 * (lane >> 4);
                uint4 o;
                u32 pk[4];
                #pragma unroll
                for (int pj = 0; pj < 4; ++pj) {
                    float v0 = s_cw[row][(cb + 2 * pj) * 3 + w];
                    float v1 = s_cw[row][(cb + 2 * pj + 1) * 3 + w];
                    pk[pj] = packbf(v0, v1);
                }
                o.x = pk[0]; o.y = pk[1]; o.z = pk[2]; o.w = pk[3];
                size_t off = (((size_t)(kstep * 3 + w) * 8 + nt) * 64 + lane) * 8;
                *(uint4*)(wf + off) = o;
            }
        }
    }
}

// ---------------- q/k projection: 16 nodes per block; sums meanp[0..3] ----------------
__global__ __launch_bounds__(256) void qk_kernel(const float* __restrict__ meanp,
                                                 const float* __restrict__ Wq,
                                                 const float* __restrict__ bq,
                                                 const float* __restrict__ Wk,
                                                 const float* __restrict__ bk,
                                                 float* __restrict__ q,
                                                 float* __restrict__ k) {
    __shared__ float ms[16][DIN];
    int n0 = blockIdx.x * 16;
    int tid = threadIdx.x;
    const size_t PS = (size_t)NN * DIN;
    for (int i = tid; i < 16 * DIN; i += 256) {
        size_t off = (size_t)(n0 + (i >> 6)) * DIN + (i & 63);
        float s = meanp[off] + meanp[PS + off] + meanp[2 * PS + off] + meanp[3 * PS + off];
        ms[i >> 6][i & 63] = s * (1.0f / SEQ);
    }
    __syncthreads();
    int j = tid & 127;
    int g = tid >> 7;
    float accq[8], acck[8];
    float bqv = bq[j], bkv = bk[j];
    #pragma unroll
    for (int r = 0; r < 8; ++r) { accq[r] = bqv; acck[r] = bkv; }
    for (int d = 0; d < DIN; ++d) {
        float wq = Wq[d * OCN + j], wk = Wk[d * OCN + j];
        #pragma unroll
        for (int r = 0; r < 8; ++r) {
            float mv = ms[g * 8 + r][d];
            accq[r] += mv * wq;
            acck[r] += mv * wk;
        }
    }
    const float qscale = 0.088388347648318447f;  // 1/sqrt(128)
    #pragma unroll
    for (int r = 0; r < 8; ++r) {
        int nn = n0 + g * 8 + r;
        q[(size_t)nn * OCN + j] = accq[r] * qscale;
        k[(size_t)nn * OCN + j] = acck[r];
    }
}

// ---------------- per-edge attention weights (padded CSR) ----------------
__global__ __launch_bounds__(256) void alpha_kernel(const float* __restrict__ q,
                                                    const float* __restrict__ k,
                                                    const int* __restrict__ fill,
                                                    const int* __restrict__ csr,
                                                    float* __restrict__ alpha) {
    __shared__ float qs[OCN];
    __shared__ float sc[CAP];
    __shared__ int sidx[CAP];
    int n = blockIdx.x;
    int deg = fill[n];
    if (deg > CAP) deg = CAP;
    int start = n << 6;
    int tid = threadIdx.x;
    if (tid < OCN) qs[tid] = q[(size_t)n * OCN + tid];
    if (tid < deg) sidx[tid] = csr[start + tid];
    __syncthreads();
    int lane = tid & 63;
    int wv = tid >> 6;
    for (int i = wv; i < deg; i += 4) {
        const float* kk = k + (size_t)sidx[i] * OCN;
        float p = kk[lane] * qs[lane] + kk[lane + 64] * qs[lane + 64];
        #pragma unroll
        for (int off = 32; off; off >>= 1) p += __shfl_down(p, off);
        if (lane == 0) sc[i] = p;
    }
    __syncthreads();
    float m = -1e30f;
    for (int i = 0; i < deg; ++i) m = fmaxf(m, sc[i]);
    __syncthreads();
    if (tid < deg) sc[tid] = __expf(sc[tid] - m);
    __syncthreads();
    float ssum = 0.f;
    for (int i = 0; i < deg; ++i) ssum += sc[i];
    float inv = (deg > 0) ? (1.0f / ssum) : 0.f;
    if (tid < deg) alpha[start + tid] = sc[tid] * inv;
}

// ---------------- gather: 4 nodes per wave, 4 interleaved pipelined chains, XCD-pinned ----------------
__global__ __launch_bounds__(256) void gather2_kernel(const u16* __restrict__ xt,
                                                      const float* __restrict__ alpha,
                                                      const int* __restrict__ fill,
                                                      const int* __restrict__ csr,
                                                      u16* __restrict__ yb) {
    int bid = blockIdx.x;
    int ch = bid & 7;
    int ng = bid >> 3;              // 0..206
    int wid = threadIdx.x >> 6;
    int lane = threadIdx.x & 63;
    int n0 = ng * 16 + wid * 4;
    int t0 = ch * TCH;
    int t = lane >> 3;
    int dg = lane & 7;
    const u16* xbase = xt + ((size_t)(t0 + t) * NN) * DIN + (dg << 3);

    int bb[4], cc[4];
    int sL[4]; float aL[4];
    int mx = 0;
    #pragma unroll
    for (int j = 0; j < 4; ++j) {
        int n = n0 + j;
        bb[j] = n / CID; cc[j] = n - bb[j] * CID;
        int deg = fill[n]; if (deg > CAP) deg = CAP;
        int st = n << 6;
        sL[j] = 0; aL[j] = 0.f;
        if (lane < deg) { sL[j] = csr[st + lane] << 6; aL[j] = alpha[st + lane]; }
        mx = (deg > mx) ? deg : mx;
    }

    float acc[4][8];
    #pragma unroll
    for (int j = 0; j < 4; ++j)
        #pragma unroll
        for (int d = 0; d < 8; ++d) acc[j][d] = 0.f;

    if (mx > 0) {
        float a0[4]; uint4 v0[4];
        #pragma unroll
        for (int j = 0; j < 4; ++j) {
            a0[j] = __shfl(aL[j], 0);
            v0[j] = *(const uint4*)(xbase + __shfl(sL[j], 0));
        }
        for (int i = 1; i < mx; ++i) {
            float a1[4]; uint4 v1[4];
            #pragma unroll
            for (int j = 0; j < 4; ++j) {
                a1[j] = __shfl(aL[j], i);
                v1[j] = *(const uint4*)(xbase + __shfl(sL[j], i));
            }
            #pragma unroll
            for (int j = 0; j < 4; ++j) {
                fma8(acc[j], a0[j], v0[j]);
                a0[j] = a1[j]; v0[j] = v1[j];
            }
        }
        #pragma unroll
        for (int j = 0; j < 4; ++j) fma8(acc[j], a0[j], v0[j]);
    }
    #pragma unroll
    for (int j = 0; j < 4; ++j) {
        uint4 o;
        o.x = packbf(acc[j][0], acc[j][1]);
        o.y = packbf(acc[j][2], acc[j][3]);
        o.z = packbf(acc[j][4], acc[j][5]);
        o.w = packbf(acc[j][6], acc[j][7]);
        *(uint4*)(yb + ((size_t)bb[j] * SEQ + t0 + t) * ICD + cc[j] * DIN + (dg << 3)) = o;
    }
}

// ---------------- conv1d as MFMA GEMM: 64t x 128oc per block, split-K(XCD-pinned), grid 512 ----------------
// r11-form (known-good): waves = (t-half, oc-half), 2 t-tiles x 4 nt = 24 MFMA / 18 loads
// per kstep, register double-buffer, kc = xcd + 8*khi for per-XCD L2-resident wf slices.
__global__ __launch_bounds__(256) void conv_kernel(const u16* __restrict__ yb,
                                                   const u16* __restrict__ wf,
                                                   float* __restrict__ partial) {
    int bid = blockIdx.x;
    int xcd = bid & 7;
    int rest = bid >> 3;               // 0..63
    int khi = rest & 3;
    int b = rest >> 2;                 // 0..15
    int kc = xcd + (khi << 3);         // 0..31
    int tid = threadIdx.x;
    int lane = tid & 63;
    int wid = tid >> 6;
    int th = wid & 1;                  // t half: 0/32
    int nh = wid >> 1;                 // oc half: 0/64
    int lrow = lane & 15;
    int lq = lane >> 4;
    int tbase = th * 32;

    f32x4 acc[2][4];
    #pragma unroll
    for (int tt = 0; tt < 2; ++tt)
        #pragma unroll
        for (int n = 0; n < 4; ++n) acc[tt][n] = (f32x4){0.f, 0.f, 0.f, 0.f};

    const u16* ybA = yb + (size_t)b * SEQ * ICD + lq * 8;
    const u16* wfL = wf + (size_t)lane * 8 + ((size_t)nh * 4 * 64) * 8;
    int ks0 = kc * KSPC;

    bf16x8 aA[6], bA[12], aB[6], bB[12];

#define LOAD_AB(aR, bR, KS) do {                                              \
    int kstep_ = ks0 + (KS);                                                  \
    int ic0_ = kstep_ * 32;                                                   \
    _Pragma("unroll")                                                         \
    for (int tt_ = 0; tt_ < 2; ++tt_) {                                       \
        _Pragma("unroll")                                                     \
        for (int w_ = 0; w_ < 3; ++w_) {                                      \
            int ts_ = tbase + tt_ * 16 + lrow + w_ - 1;                       \
            bf16x8 av_ = {0, 0, 0, 0, 0, 0, 0, 0};                            \
            if ((unsigned)ts_ < SEQ)                                          \
                av_ = *(const bf16x8*)(ybA + (size_t)ts_ * ICD + ic0_);       \
            aR[tt_ * 3 + w_] = av_;                                           \
        }                                                                     \
    }                                                                         \
    const u16* wfp_ = wfL + (size_t)kstep_ * WFSTEP;                          \
    _Pragma("unroll")                                                         \
    for (int w_ = 0; w_ < 3; ++w_) {                                          \
        _Pragma("unroll")                                                     \
        for (int n_ = 0; n_ < 4; ++n_)                                        \
            bR[w_ * 4 + n_] = *(const bf16x8*)(wfp_ + (size_t)((w_ * 8 + n_) * 64) * 8); \
    }                                                                         \
} while (0)

#define COMPUTE(aR, bR) do {                                                  \
    _Pragma("unroll")                                                         \
    for (int w_ = 0; w_ < 3; ++w_) {                                          \
        _Pragma("unroll")                                                     \
        for (int tt_ = 0; tt_ < 2; ++tt_) {                                   \
            _Pragma("unroll")                                                 \
            for (int n_ = 0; n_ < 4; ++n_)                                    \
                acc[tt_][n_] = __builtin_amdgcn_mfma_f32_16x16x32_bf16(       \
                    aR[tt_ * 3 + w_], bR[w_ * 4 + n_], acc[tt_][n_], 0, 0, 0);\
        }                                                                     \
    }                                                                         \
} while (0)

    LOAD_AB(aA, bA, 0);
    #pragma unroll
    for (int ks = 0; ks < KSPC - 1; ks += 2) {
        LOAD_AB(aB, bB, ks + 1);
        COMPUTE(aA, bA);
        LOAD_AB(aA, bA, ks + 2);
        COMPUTE(aB, bB);
    }
    COMPUTE(aA, bA);   // ks = KSPC-1 (12)

    float* pp = partial + (size_t)kc * ((size_t)BZ * SEQ * OCN) + (size_t)b * SEQ * OCN + nh * 64;
    #pragma unroll
    for (int tt = 0; tt < 2; ++tt) {
        #pragma unroll
        for (int n = 0; n < 4; ++n) {
            #pragma unroll
            for (int r = 0; r < 4; ++r) {
                int t = tbase + tt * 16 + lq * 4 + r;
                pp[(size_t)t * OCN + n * 16 + lrow] = acc[tt][n][r];
            }
        }
    }
#undef LOAD_AB
#undef COMPUTE
}

// ---------------- split-K reduce (float4) ----------------
__global__ __launch_bounds__(256) void reduce_kernel(const float* __restrict__ partial,
                                                     float* __restrict__ out) {
    int i = (blockIdx.x * 256 + threadIdx.x) * 4;
    float4 s = make_float4(0.f, 0.f, 0.f, 0.f);
    #pragma unroll
    for (int kc = 0; kc < NKC; ++kc) {
        float4 v = *(const float4*)(partial + (size_t)kc * 131072 + i);
        s.x += v.x; s.y += v.y; s.z += v.z; s.w += v.w;
    }
    *(float4*)(out + i) = s;
}

extern "C" void kernel_launch(void* const* d_in, const int* in_sizes, int n_in,
                              void* d_out, int out_size, void* d_ws, size_t ws_size,
                              hipStream_t stream) {
    const float* x   = (const float*)d_in[0];
    const float* Wq  = (const float*)d_in[1];
    const float* bqv = (const float*)d_in[2];
    const float* Wk  = (const float*)d_in[3];
    const float* bkv = (const float*)d_in[4];
    const float* cw  = (const float*)d_in[5];
    const int* esrc  = (const int*)d_in[6];
    const int* edst  = (const int*)d_in[7];

    char* ws = (char*)d_ws;
    size_t o = 0;
    auto alloc = [&](size_t bytes) {
        void* p = ws + o;
        o += (bytes + 255) & ~(size_t)255;
        return p;
    };
    u16*   xt    = (u16*)alloc(XTOT * 2);                 // 27.1 MB (aliased by partial after gather2)
    u16*   yb    = (u16*)alloc(XTOT * 2);                 // 27.1 MB
    u16*   wf    = (u16*)alloc((size_t)NKPAD * 3 * 8 * 64 * 8 * 2);  // 10.2 MB
    float* meanp = (float*)alloc((size_t)4 * NN * DIN * 4);
    float* q     = (float*)alloc((size_t)NN * OCN * 4);
    float* k     = (float*)alloc((size_t)NN * OCN * 4);
    int*   fill  = (int*)alloc((size_t)NN * 4);
    int*   csr   = (int*)alloc((size_t)NN * CAP * 4);     // padded CSR
    float* alpha = (float*)alloc((size_t)NN * CAP * 4);   // padded alpha
    float* partial = (float*)xt;   // alias: xt dead after gather2

    zero_kernel<<<dim3(1), dim3(256), 0, stream>>>(fill, NN);
    k1_kernel<<<dim3(CVB + SCB + WPB), dim3(256), 0, stream>>>(x, xt, meanp, esrc, edst, fill, csr, cw, wf);
    qk_kernel<<<dim3(NN / 16), dim3(256), 0, stream>>>(meanp, Wq, bqv, Wk, bkv, q, k);
    alpha_kernel<<<dim3(NN), dim3(256), 0, stream>>>(q, k, fill, csr, alpha);
    gather2_kernel<<<dim3((NN / 16) * NCHUNK), dim3(256), 0, stream>>>(xt, alpha, fill, csr, yb);
    conv_kernel<<<dim3(512), dim3(256), 0, stream>>>(yb, wf, partial);
    reduce_kernel<<<dim3(131072 / 4 / 256), dim3(256), 0, stream>>>(partial, (float*)d_out);
}

// Round 17
// 118.316 us; speedup vs baseline: 1.0529x; 1.0529x over previous
//
#include <hip/hip_runtime.h>
#include <hip/hip_bf16.h>
#include <math.h>

#define BZ 16
#define SEQ 64
#define CID 207
#define DIN 64
#define OCN 128
#define NN (BZ*CID)        // 3312
#define NE (NN*16)         // 52992
#define ICD (CID*DIN)      // 13248
#define KW 3
#define NKPAD 416          // kstep padded to 32*13
#define NKC 32             // K-split chunks
#define KSPC 13            // ksteps per chunk
#define XTOT ((size_t)BZ*SEQ*ICD)   // 13565952
#define TCH 8              // t-chunk for gather
#define NCHUNK (SEQ/TCH)   // 8
#define CAP 64             // padded CSR capacity per node (max observed deg ~45)
#define WFSTEP (3*8*64*8)  // wf elems per kstep = 12288

// k1 block ranges: cvtmean [0,832) | scatter [832,1039) | wprep [1039,2703)
#define CVB 832
#define SCB 207
#define WPB (NKPAD*4)

typedef __attribute__((ext_vector_type(8))) short bf16x8;
typedef __attribute__((ext_vector_type(4))) float f32x4;
typedef unsigned short u16;
typedef unsigned int u32;

__device__ __forceinline__ float bflo(u32 u) {
    u32 v = u << 16;
    return __builtin_bit_cast(float, v);
}
__device__ __forceinline__ float bfhi(u32 u) {
    u32 v = u & 0xFFFF0000u;
    return __builtin_bit_cast(float, v);
}
__device__ __forceinline__ u16 f2bf(float f) {
    __hip_bfloat16 h = __float2bfloat16(f);
    return __builtin_bit_cast(u16, h);
}
__device__ __forceinline__ u32 packbf(float f0, float f1) {
    return ((u32)f2bf(f1) << 16) | (u32)f2bf(f0);
}
__device__ __forceinline__ void fma8(float* acc, float a, uint4 v) {
    acc[0] += a * bflo(v.x); acc[1] += a * bfhi(v.x);
    acc[2] += a * bflo(v.y); acc[3] += a * bfhi(v.y);
    acc[4] += a * bflo(v.z); acc[5] += a * bfhi(v.z);
    acc[6] += a * bflo(v.w); acc[7] += a * bfhi(v.w);
}

// ---------------- tiny zero kernel ----------------
__global__ __launch_bounds__(256) void zero_kernel(int* __restrict__ p, int n) {
    int i = threadIdx.x;
    for (; i < n; i += 256) p[i] = 0;
}

// ---------------- k1: cvtmean(t-split x4) | scatter(padded CSR) | wprep(32-oc) ----------------
__global__ __launch_bounds__(256) void k1_kernel(const float* __restrict__ x,
                                                 u16* __restrict__ xt,
                                                 float* __restrict__ meanp,
                                                 const int* __restrict__ esrc,
                                                 const int* __restrict__ edst,
                                                 int* __restrict__ fill,
                                                 int* __restrict__ csr,
                                                 const float* __restrict__ cw,
                                                 u16* __restrict__ wf) {
    __shared__ float s_cw[32][100];   // wprep scratch, 12.8 KB
    int bid = blockIdx.x;
    int tid = threadIdx.x;
    if (bid < CVB) {
        // ---- cvtmean: 16 t's per block; partial sum -> meanp[tq] ----
        int bb = bid / 52;
        int rem = bid - bb * 52;
        int cg = rem >> 2;            // 0..12
        int tq = rem & 3;             // t-quarter
        int cl = tid >> 4;
        int dq = (tid & 15) << 2;
        int c = cg * 16 + cl;
        if (c >= CID) return;
        int n = bb * CID + c;
        const float* px = x + (size_t)bb * SEQ * ICD + (size_t)(tq * 16) * ICD + (size_t)c * DIN + dq;
        u16* pxt = xt + ((size_t)(tq * 16) * NN + n) * DIN + dq;
        float ax = 0.f, ay = 0.f, az = 0.f, aw = 0.f;
        #pragma unroll 4
        for (int t = 0; t < 16; ++t) {
            float4 v = *(const float4*)(px + (size_t)t * ICD);
            ax += v.x; ay += v.y; az += v.z; aw += v.w;
            uint2 w2;
            w2.x = packbf(v.x, v.y);
            w2.y = packbf(v.z, v.w);
            *(uint2*)(pxt + (size_t)t * NN * DIN) = w2;
        }
        *(float4*)(meanp + ((size_t)tq * NN + n) * DIN + dq) = make_float4(ax, ay, az, aw);
    } else if (bid < CVB + SCB) {
        // ---- scatter into padded CSR (fill zeroed by zero_kernel; fill[n] becomes deg[n]) ----
        int e = (bid - CVB) * 256 + tid;   // exactly NE
        int d0 = edst[e];
        int pos = atomicAdd(&fill[d0], 1);
        if (pos < CAP) csr[(d0 << 6) + pos] = esrc[e];
    } else {
        // ---- wprep: conv weight -> MFMA B-fragment layout, 32 oc (2 nt) per block ----
        int wkb = bid - (CVB + SCB);
        int kstep = wkb >> 2;             // 0..415
        int p = wkb & 3;                  // oc quarter
        int ic0 = kstep * 32;
        int col0 = ic0 * 3;
        {
            int oc_l = tid >> 3;
            int seg = tid & 7;
            const float* src = cw + (size_t)(p * 32 + oc_l) * (ICD * KW) + col0 + seg * 12;
            #pragma unroll
            for (int uu = 0; uu < 12; ++uu) {
                int col = seg * 12 + uu;
                float v = (col0 + col < ICD * 3) ? src[uu] : 0.f;
                s_cw[oc_l][col] = v;
            }
        }
        __syncthreads();
        #pragma unroll
        for (int r = 0; r < 2; ++r) {
            int f = tid + 256 * r;        // 0..511, use 0..383
            if (f < 384) {
                int lane = f & 63;
                int g = f >> 6;           // 0..5
                int ntl = g & 1;
                int w = g >> 1;
                int nt = p * 2 + ntl;
                int row = ntl * 16 + (lane & 15);
                int cb = 8 * (lane >> 4);
                uint4 o;
                u32 pk[4];
                #pragma unroll
                for (int pj = 0; pj < 4; ++pj) {
                    float v0 = s_cw[row][(cb + 2 * pj) * 3 + w];
                    float v1 = s_cw[row][(cb + 2 * pj + 1) * 3 + w];
                    pk[pj] = packbf(v0, v1);
                }
                o.x = pk[0]; o.y = pk[1]; o.z = pk[2]; o.w = pk[3];
                size_t off = (((size_t)(kstep * 3 + w) * 8 + nt) * 64 + lane) * 8;
                *(uint4*)(wf + off) = o;
            }
        }
    }
}

// ---------------- q/k projection: 16 nodes per block; sums meanp[0..3] ----------------
__global__ __launch_bounds__(256) void qk_kernel(const float* __restrict__ meanp,
                                                 const float* __restrict__ Wq,
                                                 const float* __restrict__ bq,
                                                 const float* __restrict__ Wk,
                                                 const float* __restrict__ bk,
                                                 float* __restrict__ q,
                                                 float* __restrict__ k) {
    __shared__ float ms[16][DIN];
    int n0 = blockIdx.x * 16;
    int tid = threadIdx.x;
    const size_t PS = (size_t)NN * DIN;
    for (int i = tid; i < 16 * DIN; i += 256) {
        size_t off = (size_t)(n0 + (i >> 6)) * DIN + (i & 63);
        float s = meanp[off] + meanp[PS + off] + meanp[2 * PS + off] + meanp[3 * PS + off];
        ms[i >> 6][i & 63] = s * (1.0f / SEQ);
    }
    __syncthreads();
    int j = tid & 127;
    int g = tid >> 7;
    float accq[8], acck[8];
    float bqv = bq[j], bkv = bk[j];
    #pragma unroll
    for (int r = 0; r < 8; ++r) { accq[r] = bqv; acck[r] = bkv; }
    for (int d = 0; d < DIN; ++d) {
        float wq = Wq[d * OCN + j], wk = Wk[d * OCN + j];
        #pragma unroll
        for (int r = 0; r < 8; ++r) {
            float mv = ms[g * 8 + r][d];
            accq[r] += mv * wq;
            acck[r] += mv * wk;
        }
    }
    const float qscale = 0.088388347648318447f;  // 1/sqrt(128)
    #pragma unroll
    for (int r = 0; r < 8; ++r) {
        int nn = n0 + g * 8 + r;
        q[(size_t)nn * OCN + j] = accq[r] * qscale;
        k[(size_t)nn * OCN + j] = acck[r];
    }
}

// ---------------- per-edge attention weights (padded CSR) ----------------
__global__ __launch_bounds__(256) void alpha_kernel(const float* __restrict__ q,
                                                    const float* __restrict__ k,
                                                    const int* __restrict__ fill,
                                                    const int* __restrict__ csr,
                                                    float* __restrict__ alpha) {
    __shared__ float qs[OCN];
    __shared__ float sc[CAP];
    __shared__ int sidx[CAP];
    int n = blockIdx.x;
    int deg = fill[n];
    if (deg > CAP) deg = CAP;
    int start = n << 6;
    int tid = threadIdx.x;
    if (tid < OCN) qs[tid] = q[(size_t)n * OCN + tid];
    if (tid < deg) sidx[tid] = csr[start + tid];
    __syncthreads();
    int lane = tid & 63;
    int wv = tid >> 6;
    for (int i = wv; i < deg; i += 4) {
        const float* kk = k + (size_t)sidx[i] * OCN;
        float p = kk[lane] * qs[lane] + kk[lane + 64] * qs[lane + 64];
        #pragma unroll
        for (int off = 32; off; off >>= 1) p += __shfl_down(p, off);
        if (lane == 0) sc[i] = p;
    }
    __syncthreads();
    float m = -1e30f;
    for (int i = 0; i < deg; ++i) m = fmaxf(m, sc[i]);
    __syncthreads();
    if (tid < deg) sc[tid] = __expf(sc[tid] - m);
    __syncthreads();
    float ssum = 0.f;
    for (int i = 0; i < deg; ++i) ssum += sc[i];
    float inv = (deg > 0) ? (1.0f / ssum) : 0.f;
    if (tid < deg) alpha[start + tid] = sc[tid] * inv;
}

// ---------------- gather: 2 nodes per wave, interleaved pipelined chains, XCD-pinned ----------------
__global__ __launch_bounds__(256) void gather2_kernel(const u16* __restrict__ xt,
                                                      const float* __restrict__ alpha,
                                                      const int* __restrict__ fill,
                                                      const int* __restrict__ csr,
                                                      u16* __restrict__ yb) {
    int bid = blockIdx.x;
    int ch = bid & 7;
    int ng = bid >> 3;              // 0..413
    int wid = threadIdx.x >> 6;
    int lane = threadIdx.x & 63;
    int na = ng * 8 + wid * 2;
    int nb = na + 1;
    int t0 = ch * TCH;
    int t = lane >> 3;
    int dg = lane & 7;
    const u16* xbase = xt + ((size_t)(t0 + t) * NN) * DIN + (dg << 3);

    int ba = na / CID, ca = na - ba * CID;
    int bb2 = nb / CID, cb = nb - bb2 * CID;
    int dega = fill[na]; if (dega > CAP) dega = CAP;
    int degb = fill[nb]; if (degb > CAP) degb = CAP;
    int sta = na << 6, stb = nb << 6;

    int sA = 0; float aA = 0.f;
    if (lane < dega) { sA = csr[sta + lane] << 6; aA = alpha[sta + lane]; }
    int sB = 0; float aB = 0.f;
    if (lane < degb) { sB = csr[stb + lane] << 6; aB = alpha[stb + lane]; }
    int mx = (dega > degb) ? dega : degb;

    float acca[8], accb[8];
    #pragma unroll
    for (int j = 0; j < 8; ++j) { acca[j] = 0.f; accb[j] = 0.f; }

    if (mx > 0) {
        float a0a = __shfl(aA, 0);
        float a0b = __shfl(aB, 0);
        uint4 v0a = *(const uint4*)(xbase + __shfl(sA, 0));
        uint4 v0b = *(const uint4*)(xbase + __shfl(sB, 0));
        for (int i = 1; i < mx; ++i) {
            float a1a = __shfl(aA, i);
            float a1b = __shfl(aB, i);
            uint4 v1a = *(const uint4*)(xbase + __shfl(sA, i));
            uint4 v1b = *(const uint4*)(xbase + __shfl(sB, i));
            fma8(acca, a0a, v0a);
            fma8(accb, a0b, v0b);
            a0a = a1a; v0a = v1a;
            a0b = a1b; v0b = v1b;
        }
        fma8(acca, a0a, v0a);
        fma8(accb, a0b, v0b);
    }
    uint4 oa, ob;
    oa.x = packbf(acca[0], acca[1]); oa.y = packbf(acca[2], acca[3]);
    oa.z = packbf(acca[4], acca[5]); oa.w = packbf(acca[6], acca[7]);
    ob.x = packbf(accb[0], accb[1]); ob.y = packbf(accb[2], accb[3]);
    ob.z = packbf(accb[4], accb[5]); ob.w = packbf(accb[6], accb[7]);
    *(uint4*)(yb + ((size_t)ba * SEQ + t0 + t) * ICD + ca * DIN + (dg << 3)) = oa;
    *(uint4*)(yb + ((size_t)bb2 * SEQ + t0 + t) * ICD + cb * DIN + (dg << 3)) = ob;
}

// ---------------- conv1d as MFMA GEMM: 64t x 128oc per block, split-K(XCD-pinned), grid 512 ----------------
__global__ __launch_bounds__(256) void conv_kernel(const u16* __restrict__ yb,
                                                   const u16* __restrict__ wf,
                                                   float* __restrict__ partial) {
    int bid = blockIdx.x;
    int xcd = bid & 7;
    int rest = bid >> 3;
    int khi = rest & 3;
    int b = rest >> 2;
    int kc = xcd + (khi << 3);
    int tid = threadIdx.x;
    int lane = tid & 63;
    int wid = tid >> 6;
    int th = wid & 1;
    int nh = wid >> 1;
    int lrow = lane & 15;
    int lq = lane >> 4;
    int tbase = th * 32;

    f32x4 acc[2][4];
    #pragma unroll
    for (int tt = 0; tt < 2; ++tt)
        #pragma unroll
        for (int n = 0; n < 4; ++n) acc[tt][n] = (f32x4){0.f, 0.f, 0.f, 0.f};

    const u16* ybA = yb + (size_t)b * SEQ * ICD + lq * 8;
    const u16* wfL = wf + (size_t)lane * 8 + ((size_t)nh * 4 * 64) * 8;
    int ks0 = kc * KSPC;

    bf16x8 aA[6], bA[12], aB[6], bB[12];

#define LOAD_AB(aR, bR, KS) do {                                              \
    int kstep_ = ks0 + (KS);                                                  \
    int ic0_ = kstep_ * 32;                                                   \
    _Pragma("unroll")                                                         \
    for (int tt_ = 0; tt_ < 2; ++tt_) {                                       \
        _Pragma("unroll")                                                     \
        for (int w_ = 0; w_ < 3; ++w_) {                                      \
            int ts_ = tbase + tt_ * 16 + lrow + w_ - 1;                       \
            bf16x8 av_ = {0, 0, 0, 0, 0, 0, 0, 0};                            \
            if ((unsigned)ts_ < SEQ)                                          \
                av_ = *(const bf16x8*)(ybA + (size_t)ts_ * ICD + ic0_);       \
            aR[tt_ * 3 + w_] = av_;                                           \
        }                                                                     \
    }                                                                         \
    const u16* wfp_ = wfL + (size_t)kstep_ * WFSTEP;                          \
    _Pragma("unroll")                                                         \
    for (int w_ = 0; w_ < 3; ++w_) {                                          \
        _Pragma("unroll")                                                     \
        for (int n_ = 0; n_ < 4; ++n_)                                        \
            bR[w_ * 4 + n_] = *(const bf16x8*)(wfp_ + (size_t)((w_ * 8 + n_) * 64) * 8); \
    }                                                                         \
} while (0)

#define COMPUTE(aR, bR) do {                                                  \
    _Pragma("unroll")                                                         \
    for (int w_ = 0; w_ < 3; ++w_) {                                          \
        _Pragma("unroll")                                                     \
        for (int tt_ = 0; tt_ < 2; ++tt_) {                                   \
            _Pragma("unroll")                                                 \
            for (int n_ = 0; n_ < 4; ++n_)                                    \
                acc[tt_][n_] = __builtin_amdgcn_mfma_f32_16x16x32_bf16(       \
                    aR[tt_ * 3 + w_], bR[w_ * 4 + n_], acc[tt_][n_], 0, 0, 0);\
        }                                                                     \
    }                                                                         \
} while (0)

    LOAD_AB(aA, bA, 0);
    #pragma unroll
    for (int ks = 0; ks < KSPC - 1; ks += 2) {
        LOAD_AB(aB, bB, ks + 1);
        COMPUTE(aA, bA);
        LOAD_AB(aA, bA, ks + 2);
        COMPUTE(aB, bB);
    }
    COMPUTE(aA, bA);

    float* pp = partial + (size_t)kc * ((size_t)BZ * SEQ * OCN) + (size_t)b * SEQ * OCN + nh * 64;
    #pragma unroll
    for (int tt = 0; tt < 2; ++tt) {
        #pragma unroll
        for (int n = 0; n < 4; ++n) {
            #pragma unroll
            for (int r = 0; r < 4; ++r) {
                int t = tbase + tt * 16 + lq * 4 + r;
                pp[(size_t)t * OCN + n * 16 + lrow] = acc[tt][n][r];
            }
        }
    }
#undef LOAD_AB
#undef COMPUTE
}

// ---------------- split-K reduce (float4) ----------------
__global__ __launch_bounds__(256) void reduce_kernel(const float* __restrict__ partial,
                                                     float* __restrict__ out) {
    int i = (blockIdx.x * 256 + threadIdx.x) * 4;
    float4 s = make_float4(0.f, 0.f, 0.f, 0.f);
    #pragma unroll
    for (int kc = 0; kc < NKC; ++kc) {
        float4 v = *(const float4*)(partial + (size_t)kc * 131072 + i);
        s.x += v.x; s.y += v.y; s.z += v.z; s.w += v.w;
    }
    *(float4*)(out + i) = s;
}

extern "C" void kernel_launch(void* const* d_in, const int* in_sizes, int n_in,
                              void* d_out, int out_size, void* d_ws, size_t ws_size,
                              hipStream_t stream) {
    const float* x   = (const float*)d_in[0];
    const float* Wq  = (const float*)d_in[1];
    const float* bqv = (const float*)d_in[2];
    const float* Wk  = (const float*)d_in[3];
    const float* bkv = (const float*)d_in[4];
    const float* cw  = (const float*)d_in[5];
    const int* esrc  = (const int*)d_in[6];
    const int* edst  = (const int*)d_in[7];

    char* ws = (char*)d_ws;
    size_t o = 0;
    auto alloc = [&](size_t bytes) {
        void* p = ws + o;
        o += (bytes + 255) & ~(size_t)255;
        return p;
    };
    u16*   xt    = (u16*)alloc(XTOT * 2);                 // 27.1 MB (aliased by partial after gather2)
    u16*   yb    = (u16*)alloc(XTOT * 2);                 // 27.1 MB
    u16*   wf    = (u16*)alloc((size_t)NKPAD * 3 * 8 * 64 * 8 * 2);  // 10.2 MB
    float* meanp = (float*)alloc((size_t)4 * NN * DIN * 4);
    float* q     = (float*)alloc((size_t)NN * OCN * 4);
    float* k     = (float*)alloc((size_t)NN * OCN * 4);
    int*   fill  = (int*)alloc((size_t)NN * 4);
    int*   csr   = (int*)alloc((size_t)NN * CAP * 4);     // padded CSR
    float* alpha = (float*)alloc((size_t)NN * CAP * 4);   // padded alpha
    float* partial = (float*)xt;   // alias: xt dead after gather2

    zero_kernel<<<dim3(1), dim3(256), 0, stream>>>(fill, NN);
    k1_kernel<<<dim3(CVB + SCB + WPB), dim3(256), 0, stream>>>(x, xt, meanp, esrc, edst, fill, csr, cw, wf);
    qk_kernel<<<dim3(NN / 16), dim3(256), 0, stream>>>(meanp, Wq, bqv, Wk, bkv, q, k);
    alpha_kernel<<<dim3(NN), dim3(256), 0, stream>>>(q, k, fill, csr, alpha);
    gather2_kernel<<<dim3((NN / 8) * NCHUNK), dim3(256), 0, stream>>>(xt, alpha, fill, csr, yb);
    conv_kernel<<<dim3(512), dim3(256), 0, stream>>>(yb, wf, partial);
    reduce_kernel<<<dim3(131072 / 4 / 256), dim3(256), 0, stream>>>(partial, (float*)d_out);
}